// Round 3
// baseline (291.063 us; speedup 1.0000x reference)
//
#include <hip/hip_runtime.h>

// ---------------------------------------------------------------------------
// GNN 2-layer via bf16 MFMA + CSR gather (no atomics in hot path).
// Round 3:
//  - gathers chunked over feature dim (4 x 32 cols): each chunk's msg slice
//    is 3.2 MB -> L2-resident per XCD (vs 12.8 MB thrashing 4 MiB L2).
//    Chunk-major grid so all XCDs work the same slice at once.
//  - gemm1 split across K3 (||binC) and K4 (||binD) to cover both bin stages.
//  - binD DCAP 8192->6144 (27 KB LDS, 5 blocks/CU; global fallback kept).
// Launches:
//   K1: pack_w || binA
//   K2: binB (merged scans)
//   K3: binC || gemm1[0..GB_A)
//   K4: binD || gemm1[GB_A..)
//   K5: gather_chunk (layer 1) -> agg1bf (bf16)
//   K6: gemm2_mfma -> out[:,128:] fp32 + m2bf
//   K7: gather_chunk (layer 2) -> out[:, :128] fp32
// ---------------------------------------------------------------------------

#define D 128
#define CBLK 256         // coarse-binning blocks (phases A and C)
#define DCAP 6144        // max edges per coarse bucket for LDS path

typedef __attribute__((ext_vector_type(8))) short short8;
typedef __attribute__((ext_vector_type(4))) float float4v;
typedef unsigned short ushort_t;
typedef unsigned int uint_t;

static __device__ __forceinline__ ushort_t f2bf(float f) {
    uint_t u = __builtin_bit_cast(uint_t, f);
    u += 0x7FFFu + ((u >> 16) & 1u);           // RNE
    return (ushort_t)(u >> 16);
}
static __device__ __forceinline__ float bfhi(uint_t u) {
    return __builtin_bit_cast(float, u & 0xFFFF0000u);
}
static __device__ __forceinline__ float bflo(uint_t u) {
    return __builtin_bit_cast(float, u << 16);
}

// ---------------- shared gemm1 body (m1 = bf16(X @ W1 + b1)) ----------------
static __device__ __forceinline__ void gemm1_body(
    const float* __restrict__ X, const ushort_t* __restrict__ Wp,
    const float* __restrict__ bias, ushort_t* __restrict__ Ybf,
    int N, int gb)
{
    const int wave = threadIdx.x >> 6;
    const int lane = threadIdx.x & 63;
    const int quad = lane >> 4;
    const int l16  = lane & 15;
    const int r0   = gb * 128 + wave * 32;

    float4v acc[2][8];
    #pragma unroll
    for (int cg = 0; cg < 8; ++cg) {
        float bv = bias[cg * 16 + l16];
        float4v b4 = {bv, bv, bv, bv};
        acc[0][cg] = b4; acc[1][cg] = b4;
    }

    const short8* wp8 = (const short8*)Wp;

    #pragma unroll
    for (int kb = 0; kb < 4; ++kb) {
        const int k0 = kb * 32 + quad * 8;
        short8 a[2];
        #pragma unroll
        for (int rb = 0; rb < 2; ++rb) {
            int row = r0 + rb * 16 + l16;
            if (row >= N) row = N - 1;
            const float* p = &X[(size_t)row * D + k0];
            float4 x0 = *(const float4*)p;
            float4 x1 = *(const float4*)(p + 4);
            short8 s;
            s[0] = (short)f2bf(x0.x); s[1] = (short)f2bf(x0.y);
            s[2] = (short)f2bf(x0.z); s[3] = (short)f2bf(x0.w);
            s[4] = (short)f2bf(x1.x); s[5] = (short)f2bf(x1.y);
            s[6] = (short)f2bf(x1.z); s[7] = (short)f2bf(x1.w);
            a[rb] = s;
        }
        #pragma unroll
        for (int cg = 0; cg < 8; ++cg) {
            short8 b = wp8[(kb * 8 + cg) * 64 + lane];
            acc[0][cg] = __builtin_amdgcn_mfma_f32_16x16x32_bf16(a[0], b, acc[0][cg], 0, 0, 0);
            acc[1][cg] = __builtin_amdgcn_mfma_f32_16x16x32_bf16(a[1], b, acc[1][cg], 0, 0, 0);
        }
    }

    #pragma unroll
    for (int rb = 0; rb < 2; ++rb) {
        int rowb = r0 + rb * 16 + quad * 4;
        #pragma unroll
        for (int cg = 0; cg < 8; ++cg) {
            int col = cg * 16 + l16;
            #pragma unroll
            for (int i = 0; i < 4; ++i) {
                int row = rowb + i;
                if (row < N) Ybf[(size_t)row * D + col] = f2bf(acc[rb][cg][i]);
            }
        }
    }
}

// ---------------- K1: pack both W (B-frag layout)  ||  binA -----------------
__global__ __launch_bounds__(256) void packw_binA(
    const float* __restrict__ W1, const float* __restrict__ W2,
    ushort_t* __restrict__ W1p, ushort_t* __restrict__ W2p,
    const int* __restrict__ dst, int* __restrict__ mat, int E, int NB)
{
    __shared__ int h[256];
    if (blockIdx.x < CBLK) {
        const int c = blockIdx.x;
        for (int i = threadIdx.x; i < NB; i += 256) h[i] = 0;
        __syncthreads();
        const int chunk = (E + CBLK - 1) / CBLK;
        int e0 = c * chunk, e1 = e0 + chunk; if (e1 > E) e1 = E;
        for (int e = e0 + threadIdx.x; e < e1; e += 256)
            atomicAdd(&h[dst[e] >> 8], 1);
        __syncthreads();
        for (int i = threadIdx.x; i < NB; i += 256)
            mat[i * CBLK + c] = h[i];
        return;
    }
    const int n1 = 4 * 8 * 64;
    const int n2 = 8 * 8 * 64;
    int t = (blockIdx.x - CBLK) * 256 + threadIdx.x;
    if (t >= n1 + n2) return;
    const float* W; ushort_t* Wp; int tt;
    if (t < n1) { W = W1; Wp = W1p; tt = t; }
    else        { W = W2; Wp = W2p; tt = t - n1; }
    int lane = tt & 63, cg = (tt >> 6) & 7, kb = tt >> 9;
    int krow = kb * 32 + (lane >> 4) * 8;
    int col  = cg * 16 + (lane & 15);
    #pragma unroll
    for (int j = 0; j < 8; ++j)
        Wp[(size_t)tt * 8 + j] = f2bf(W[(size_t)(krow + j) * D + col]);
}

// ---------------- K2: binB (merged B1+B2) -----------------------------------
__global__ __launch_bounds__(256) void binB(
    const int* __restrict__ mat, int* __restrict__ matc,
    int* __restrict__ bb, int* __restrict__ offs, int E, int N, int NB)
{
    __shared__ int s[256];
    __shared__ int ex[256];
    const int b = blockIdx.x;
    const int tid = threadIdx.x;

    int v = 0;
    if (tid < NB) {
        const int* row = &mat[tid * CBLK];
        for (int c = 0; c < CBLK; ++c) v += row[c];
    }
    s[tid] = v; __syncthreads();
    for (int o = 1; o < 256; o <<= 1) {
        int t = (tid >= o) ? s[tid - o] : 0;
        __syncthreads();
        s[tid] += t;
        __syncthreads();
    }
    ex[tid] = s[tid] - v;
    __syncthreads();
    if (b == 0) {
        if (tid < NB) bb[tid] = ex[tid];
        if (tid == 0) { bb[NB] = E; offs[N] = E; }
    }
    const int bbb = ex[b];

    int v2 = mat[b * CBLK + tid];
    __syncthreads();
    s[tid] = v2; __syncthreads();
    for (int o = 1; o < 256; o <<= 1) {
        int t = (tid >= o) ? s[tid - o] : 0;
        __syncthreads();
        s[tid] += t;
        __syncthreads();
    }
    matc[b * CBLK + tid] = bbb + s[tid] - v2;
}

// ---------------- K3: binC  ||  gemm1 part A --------------------------------
__global__ __launch_bounds__(256) void binC_gemm1(
    const int* __restrict__ src, const int* __restrict__ dst,
    const int* __restrict__ matc, int2* __restrict__ tmp, int E, int NB,
    const float* __restrict__ X, const ushort_t* __restrict__ Wp,
    const float* __restrict__ bias, ushort_t* __restrict__ Ybf, int N)
{
    __shared__ int base[256];
    __shared__ int lcnt[256];
    if (blockIdx.x < CBLK) {
        const int c = blockIdx.x;
        for (int i = threadIdx.x; i < NB; i += 256) {
            base[i] = matc[i * CBLK + c];
            lcnt[i] = 0;
        }
        __syncthreads();
        const int chunk = (E + CBLK - 1) / CBLK;
        int e0 = c * chunk, e1 = e0 + chunk; if (e1 > E) e1 = E;
        for (int e = e0 + threadIdx.x; e < e1; e += 256) {
            int d = dst[e];
            int b = d >> 8;
            int p = base[b] + atomicAdd(&lcnt[b], 1);
            int2 pr; pr.x = d; pr.y = src[e];
            tmp[p] = pr;
        }
        return;
    }
    gemm1_body(X, Wp, bias, Ybf, N, blockIdx.x - CBLK);
}

// ---------------- K4: binD (fine sort) || gemm1 part B ----------------------
__global__ __launch_bounds__(256) void binD_gemm1(
    const int2* __restrict__ tmp, const int* __restrict__ bb,
    int* __restrict__ offs, int* __restrict__ bsrc, int N, int NB,
    const float* __restrict__ X, const ushort_t* __restrict__ Wp,
    const float* __restrict__ bias, ushort_t* __restrict__ Ybf, int gb0)
{
    __shared__ int hist[256];
    __shared__ int foff[256];
    __shared__ int cntf[256];
    __shared__ int outS[DCAP];
    if (blockIdx.x >= (uint_t)NB) {
        gemm1_body(X, Wp, bias, Ybf, N, blockIdx.x - NB + gb0);
        return;
    }
    const int b = blockIdx.x;
    const int tid = threadIdx.x;
    const int beg = bb[b], end = bb[b + 1];
    const int cnt = end - beg;
    const int n0 = b << 8;

    hist[tid] = 0;
    __syncthreads();
    for (int i = tid; i < cnt; i += 256)
        atomicAdd(&hist[tmp[beg + i].x & 255], 1);
    __syncthreads();
    int v = hist[tid];
    __syncthreads();
    hist[tid] = v; __syncthreads();
    for (int o = 1; o < 256; o <<= 1) {
        int t = (tid >= o) ? hist[tid - o] : 0;
        __syncthreads();
        hist[tid] += t;
        __syncthreads();
    }
    foff[tid] = hist[tid] - v;
    cntf[tid] = 0;
    __syncthreads();

    int node = n0 + tid;
    if (node < N) offs[node] = beg + foff[tid];

    if (cnt <= DCAP) {
        for (int i = tid; i < cnt; i += 256) {
            int2 p = tmp[beg + i];
            int f = p.x & 255;
            int pos = foff[f] + atomicAdd(&cntf[f], 1);
            outS[pos] = p.y;
        }
        __syncthreads();
        for (int i = tid; i < cnt; i += 256)
            bsrc[beg + i] = outS[i];
    } else {
        for (int i = tid; i < cnt; i += 256) {
            int2 p = tmp[beg + i];
            int f = p.x & 255;
            int pos = foff[f] + atomicAdd(&cntf[f], 1);
            bsrc[beg + pos] = p.y;
        }
    }
}

// ---------------- K6: MFMA GEMM 2: bf16 A0/A1 -> fp32 Y + bf16 copy ---------
__global__ __launch_bounds__(256) void gemm2_mfma(
    const ushort_t* __restrict__ A0, const ushort_t* __restrict__ A1,
    const ushort_t* __restrict__ Wp, const float* __restrict__ bias,
    float* __restrict__ Yf, ushort_t* __restrict__ Ybf, int N)
{
    const int wave = threadIdx.x >> 6;
    const int lane = threadIdx.x & 63;
    const int quad = lane >> 4;
    const int l16  = lane & 15;
    const int r0   = blockIdx.x * 128 + wave * 32;

    float4v acc[2][8];
    #pragma unroll
    for (int cg = 0; cg < 8; ++cg) {
        float bv = bias[cg * 16 + l16];
        float4v b4 = {bv, bv, bv, bv};
        acc[0][cg] = b4; acc[1][cg] = b4;
    }

    const short8* wp8 = (const short8*)Wp;

    #pragma unroll
    for (int kb = 0; kb < 8; ++kb) {
        const ushort_t* __restrict__ A = (kb < 4) ? A0 : A1;
        const int k0 = (kb & 3) * 32 + quad * 8;
        short8 a[2];
        #pragma unroll
        for (int rb = 0; rb < 2; ++rb) {
            int row = r0 + rb * 16 + l16;
            if (row >= N) row = N - 1;
            a[rb] = *(const short8*)&A[(size_t)row * D + k0];
        }
        #pragma unroll
        for (int cg = 0; cg < 8; ++cg) {
            short8 b = wp8[(kb * 8 + cg) * 64 + lane];
            acc[0][cg] = __builtin_amdgcn_mfma_f32_16x16x32_bf16(a[0], b, acc[0][cg], 0, 0, 0);
            acc[1][cg] = __builtin_amdgcn_mfma_f32_16x16x32_bf16(a[1], b, acc[1][cg], 0, 0, 0);
        }
    }

    #pragma unroll
    for (int rb = 0; rb < 2; ++rb) {
        int rowb = r0 + rb * 16 + quad * 4;
        #pragma unroll
        for (int cg = 0; cg < 8; ++cg) {
            int col = cg * 16 + l16;
            #pragma unroll
            for (int i = 0; i < 4; ++i) {
                int row = rowb + i;
                if (row < N) {
                    float v = acc[rb][cg][i];
                    Yf[(size_t)row * 256 + col] = v;
                    Ybf[(size_t)row * D + col] = f2bf(v);
                }
            }
        }
    }
}

// ---------------- K5/K7: chunked gather-sum over CSR ------------------------
// Feature dim split into 4 chunks of 32 cols (64 B). blockIdx chunk-major:
// chunk = blockIdx.x / nodeBlks, so all XCDs stream the same 3.2 MB slice
// (L2-resident). Wave layout: lane = (edge e4 = lane&15, granule g = lane>>4).
// Reduce over 16 edge-lanes via shfl_xor 1/2/4/8; 4 lanes write 64 B run.
__global__ __launch_bounds__(256) void gather_chunk(
    const ushort_t* __restrict__ msg,            // [N][128] bf16
    const int* __restrict__ offs, const int* __restrict__ bsrc,
    ushort_t* __restrict__ aggB,                 // bf16 out [N][128], or null
    float* __restrict__ aggF,                    // fp32 out (stride 256), or null
    int N, int nodeBlks)
{
    const int chunk = blockIdx.x / nodeBlks;     // 0..3
    const int nb    = blockIdx.x - chunk * nodeBlks;
    const int wave  = threadIdx.x >> 6;
    const int node  = nb * 4 + wave;
    if (node >= N) return;
    const int lane = threadIdx.x & 63;
    const int e4   = lane & 15;                  // edge slot within group
    const int g4   = chunk * 4 + (lane >> 4);    // 16B granule within row

    const int beg = offs[node], end = offs[node + 1];

    float ax[4] = {0.f, 0.f, 0.f, 0.f};
    float ay[4] = {0.f, 0.f, 0.f, 0.f};
    const uint4* mp = (const uint4*)msg;         // 16 uint4 per row

    for (int base = beg; base < end; base += 16) {
        int cnt = end - base; if (cnt > 16) cnt = 16;
        if (e4 < cnt) {
            int s = bsrc[base + e4];
            uint4 u = mp[(size_t)s * 16 + g4];
            ax[0] += bflo(u.x); ay[0] += bfhi(u.x);
            ax[1] += bflo(u.y); ay[1] += bfhi(u.y);
            ax[2] += bflo(u.z); ay[2] += bfhi(u.z);
            ax[3] += bflo(u.w); ay[3] += bfhi(u.w);
        }
    }

    #pragma unroll
    for (int k = 0; k < 4; ++k) {
        #pragma unroll
        for (int m = 1; m <= 8; m <<= 1) {
            ax[k] += __shfl_xor(ax[k], m, 64);
            ay[k] += __shfl_xor(ay[k], m, 64);
        }
    }

    if (e4 == 0) {
        if (aggB) {
            uint4 o;
            o.x = (uint_t)f2bf(ax[0]) | ((uint_t)f2bf(ay[0]) << 16);
            o.y = (uint_t)f2bf(ax[1]) | ((uint_t)f2bf(ay[1]) << 16);
            o.z = (uint_t)f2bf(ax[2]) | ((uint_t)f2bf(ay[2]) << 16);
            o.w = (uint_t)f2bf(ax[3]) | ((uint_t)f2bf(ay[3]) << 16);
            ((uint4*)aggB)[(size_t)node * 16 + g4] = o;
        } else {
            float4 w0 = {ax[0], ay[0], ax[1], ay[1]};
            float4 w1 = {ax[2], ay[2], ax[3], ay[3]};
            float* p = &aggF[(size_t)node * 256 + g4 * 8];
            *(float4*)p = w0;
            *(float4*)(p + 4) = w1;
        }
    }
}

// ---------------------------------------------------------------------------
extern "C" void kernel_launch(void* const* d_in, const int* in_sizes, int n_in,
                              void* d_out, int out_size, void* d_ws, size_t ws_size,
                              hipStream_t stream) {
    const float* features = (const float*)d_in[0];
    const int*   src      = (const int*)d_in[1];
    const int*   dst      = (const int*)d_in[2];
    const float* W1       = (const float*)d_in[3];
    const float* b1       = (const float*)d_in[4];
    const float* W2       = (const float*)d_in[5];
    const float* b2       = (const float*)d_in[6];
    float* out = (float*)d_out;

    const int N = in_sizes[0] / D;   // 50000
    const int E = in_sizes[1];       // 800000
    const int NB = (N + 255) >> 8;   // 196 coarse buckets (<=256 required)

    // ws carve-up
    ushort_t* m1bf   = (ushort_t*)d_ws;                 // N*D
    ushort_t* agg1bf = m1bf + (size_t)N * D;            // N*D
    ushort_t* m2bf   = agg1bf + (size_t)N * D;          // N*D
    ushort_t* W1p    = m2bf + (size_t)N * D;            // 16384
    ushort_t* W2p    = W1p + 16384;                     // 32768
    int*  mat  = (int*)(W2p + 32768);                   // NB*CBLK (histograms)
    int*  matc = mat + (size_t)NB * CBLK;               // NB*CBLK (cursors)
    int*  bb   = matc + (size_t)NB * CBLK;              // NB+1
    int*  offs = bb + NB + 1;                           // N+1
    int2* tmp  = (int2*)(offs + N + 1);                 // E pairs
    int*  bsrc = (int*)(tmp + (size_t)E);               // E

    const int gemmBlocks = (N + 127) / 128;             // 391
    const int gbA = (gemmBlocks * 3) / 5;               // gemm1 share in K3
    const int nodeBlks = (N + 3) / 4;                   // 12500

    // K1: weight pack || coarse histogram
    packw_binA<<<CBLK + 24, 256, 0, stream>>>(W1, W2, W1p, W2p, dst, mat, E, NB);
    // K2: merged scans -> bucket bases (bb) + per-block cursors (matc)
    binB<<<NB, 256, 0, stream>>>(mat, matc, bb, offs, E, N, NB);
    // K3: coarse binning || gemm1 blocks [0, gbA)
    binC_gemm1<<<CBLK + gbA, 256, 0, stream>>>(src, dst, matc, tmp, E, NB,
                                               features, W1p, b1, m1bf, N);
    // K4: fine sort || gemm1 blocks [gbA, gemmBlocks)
    binD_gemm1<<<NB + (gemmBlocks - gbA), 256, 0, stream>>>(
        tmp, bb, offs, bsrc, N, NB, features, W1p, b1, m1bf, gbA);
    // K5: layer-1 gather (chunked) -> agg1bf (bf16)
    gather_chunk<<<nodeBlks * 4, 256, 0, stream>>>(m1bf, offs, bsrc,
                                                   agg1bf, nullptr, N, nodeBlks);
    // K6: layer-2 GEMM -> out[:,128:] fp32 + m2bf
    gemm2_mfma<<<gemmBlocks, 256, 0, stream>>>(agg1bf, m1bf, W2p, b2,
                                               out + D, m2bf, N);
    // K7: layer-2 gather (chunked) -> out[:, :128]
    gather_chunk<<<nodeBlks * 4, 256, 0, stream>>>(m2bf, offs, bsrc,
                                                   nullptr, out, N, nodeBlks);
}

// Round 5
// 254.008 us; speedup vs baseline: 1.1459x; 1.1459x over previous
//
#include <hip/hip_runtime.h>

// ---------------------------------------------------------------------------
// GNN 2-layer via bf16 MFMA + CSR gather.
// Round 4 resubmit (container infra failure, no GPU signal; source audited —
// no OOB / hang candidates found, grids static, graph-capture safe).
// CSR build via global-atomic counting (hist/scan/scatter) replaces the
// two-level counting sort. Gathers are the round-2 full-row form.
// Launches:
//   K1: zero(deg) || pack_w
//   K2: hist   (atomicAdd deg[dst])
//   K3: scan   (offs + cur, 196 blocks)
//   K4: scatter (bsrc via atomic cursors) || gemm1
//   K5: gather_bf (layer 1) -> agg1bf (bf16)
//   K6: gemm2_mfma -> out[:,128:] fp32 + m2bf
//   K7: gather_bf (layer 2) -> out[:, :128] fp32
// ws: m1bf | agg1bf | m2bf | W1p | W2p | deg | cur | bb(unused) | offs | tmp(unused) | bsrc
// ---------------------------------------------------------------------------

#define D 128
#define SCB 256          // scatter blocks

typedef __attribute__((ext_vector_type(8))) short short8;
typedef __attribute__((ext_vector_type(4))) float float4v;
typedef unsigned short ushort_t;
typedef unsigned int uint_t;

static __device__ __forceinline__ ushort_t f2bf(float f) {
    uint_t u = __builtin_bit_cast(uint_t, f);
    u += 0x7FFFu + ((u >> 16) & 1u);           // RNE
    return (ushort_t)(u >> 16);
}
static __device__ __forceinline__ float bfhi(uint_t u) {
    return __builtin_bit_cast(float, u & 0xFFFF0000u);
}
static __device__ __forceinline__ float bflo(uint_t u) {
    return __builtin_bit_cast(float, u << 16);
}

// ---------------- shared gemm1 body (m1 = bf16(X @ W1 + b1)) ----------------
static __device__ __forceinline__ void gemm1_body(
    const float* __restrict__ X, const ushort_t* __restrict__ Wp,
    const float* __restrict__ bias, ushort_t* __restrict__ Ybf,
    int N, int gb)
{
    const int wave = threadIdx.x >> 6;
    const int lane = threadIdx.x & 63;
    const int quad = lane >> 4;
    const int l16  = lane & 15;
    const int r0   = gb * 128 + wave * 32;

    float4v acc[2][8];
    #pragma unroll
    for (int cg = 0; cg < 8; ++cg) {
        float bv = bias[cg * 16 + l16];
        float4v b4 = {bv, bv, bv, bv};
        acc[0][cg] = b4; acc[1][cg] = b4;
    }

    const short8* wp8 = (const short8*)Wp;

    #pragma unroll
    for (int kb = 0; kb < 4; ++kb) {
        const int k0 = kb * 32 + quad * 8;
        short8 a[2];
        #pragma unroll
        for (int rb = 0; rb < 2; ++rb) {
            int row = r0 + rb * 16 + l16;
            if (row >= N) row = N - 1;
            const float* p = &X[(size_t)row * D + k0];
            float4 x0 = *(const float4*)p;
            float4 x1 = *(const float4*)(p + 4);
            short8 s;
            s[0] = (short)f2bf(x0.x); s[1] = (short)f2bf(x0.y);
            s[2] = (short)f2bf(x0.z); s[3] = (short)f2bf(x0.w);
            s[4] = (short)f2bf(x1.x); s[5] = (short)f2bf(x1.y);
            s[6] = (short)f2bf(x1.z); s[7] = (short)f2bf(x1.w);
            a[rb] = s;
        }
        #pragma unroll
        for (int cg = 0; cg < 8; ++cg) {
            short8 b = wp8[(kb * 8 + cg) * 64 + lane];
            acc[0][cg] = __builtin_amdgcn_mfma_f32_16x16x32_bf16(a[0], b, acc[0][cg], 0, 0, 0);
            acc[1][cg] = __builtin_amdgcn_mfma_f32_16x16x32_bf16(a[1], b, acc[1][cg], 0, 0, 0);
        }
    }

    #pragma unroll
    for (int rb = 0; rb < 2; ++rb) {
        int rowb = r0 + rb * 16 + quad * 4;
        #pragma unroll
        for (int cg = 0; cg < 8; ++cg) {
            int col = cg * 16 + l16;
            #pragma unroll
            for (int i = 0; i < 4; ++i) {
                int row = rowb + i;
                if (row < N) Ybf[(size_t)row * D + col] = f2bf(acc[rb][cg][i]);
            }
        }
    }
}

// ---------------- K1: zero deg  ||  pack both W (B-frag layout) -------------
__global__ __launch_bounds__(256) void zero_pack(
    const float* __restrict__ W1, const float* __restrict__ W2,
    ushort_t* __restrict__ W1p, ushort_t* __restrict__ W2p,
    int* __restrict__ deg, int ZB)
{
    if ((int)blockIdx.x < ZB) {
        deg[blockIdx.x * 256 + threadIdx.x] = 0;
        return;
    }
    const int n1 = 4 * 8 * 64;
    const int n2 = 8 * 8 * 64;
    int t = (blockIdx.x - ZB) * 256 + threadIdx.x;
    if (t >= n1 + n2) return;
    const float* W; ushort_t* Wp; int tt;
    if (t < n1) { W = W1; Wp = W1p; tt = t; }
    else        { W = W2; Wp = W2p; tt = t - n1; }
    int lane = tt & 63, cg = (tt >> 6) & 7, kb = tt >> 9;
    int krow = kb * 32 + (lane >> 4) * 8;
    int col  = cg * 16 + (lane & 15);
    #pragma unroll
    for (int j = 0; j < 8; ++j)
        Wp[(size_t)tt * 8 + j] = f2bf(W[(size_t)(krow + j) * D + col]);
}

// ---------------- K2: in-degree histogram (global atomics, L2-resident) -----
__global__ __launch_bounds__(256) void hist(const int* __restrict__ dst,
                                            int* __restrict__ deg, int E)
{
    int t = blockIdx.x * 256 + threadIdx.x;
    for (int e = t; e < E; e += 256 * 256)
        atomicAdd(&deg[dst[e]], 1);
}

// ---------------- K3: scan -> offs + cursor copy ----------------------------
// NB blocks. Each block redundantly computes per-chunk totals (thread t sums
// chunk t) + block scan -> chunk prefix; then scans its own chunk's degrees.
__global__ __launch_bounds__(256) void scanK(
    const int* __restrict__ deg, int* __restrict__ offs, int* __restrict__ cur,
    int E, int N, int NB)
{
    __shared__ int s[256];
    __shared__ int ex[256];
    const int b = blockIdx.x;
    const int tid = threadIdx.x;

    int v = 0;
    if (tid < NB) {
        const int* p = &deg[tid * 256];
        for (int i = 0; i < 256; ++i) v += p[i];
    }
    s[tid] = v; __syncthreads();
    for (int o = 1; o < 256; o <<= 1) {
        int t = (tid >= o) ? s[tid - o] : 0;
        __syncthreads();
        s[tid] += t;
        __syncthreads();
    }
    ex[tid] = s[tid] - v;
    __syncthreads();
    const int cbase = ex[b];

    int node = b * 256 + tid;
    int d = deg[node];
    __syncthreads();
    s[tid] = d; __syncthreads();
    for (int o = 1; o < 256; o <<= 1) {
        int t = (tid >= o) ? s[tid - o] : 0;
        __syncthreads();
        s[tid] += t;
        __syncthreads();
    }
    int off = cbase + s[tid] - d;
    if (node < N) { offs[node] = off; cur[node] = off; }
    if (b == 0 && tid == 0) offs[N] = E;
}

// ---------------- K4: scatter (atomic cursors)  ||  gemm1 -------------------
__global__ __launch_bounds__(256) void scatter_gemm1(
    const int* __restrict__ src, const int* __restrict__ dst,
    int* __restrict__ cur, int* __restrict__ bsrc, int E,
    const float* __restrict__ X, const ushort_t* __restrict__ Wp,
    const float* __restrict__ bias, ushort_t* __restrict__ Ybf, int N)
{
    if ((int)blockIdx.x < SCB) {
        int t = blockIdx.x * 256 + threadIdx.x;
        for (int e = t; e < E; e += SCB * 256) {
            int d = dst[e];
            int pos = atomicAdd(&cur[d], 1);
            bsrc[pos] = src[e];
        }
        return;
    }
    gemm1_body(X, Wp, bias, Ybf, N, blockIdx.x - SCB);
}

// ---------------- K6: MFMA GEMM 2: bf16 A0/A1 -> fp32 Y + bf16 copy ---------
__global__ __launch_bounds__(256) void gemm2_mfma(
    const ushort_t* __restrict__ A0, const ushort_t* __restrict__ A1,
    const ushort_t* __restrict__ Wp, const float* __restrict__ bias,
    float* __restrict__ Yf, ushort_t* __restrict__ Ybf, int N)
{
    const int wave = threadIdx.x >> 6;
    const int lane = threadIdx.x & 63;
    const int quad = lane >> 4;
    const int l16  = lane & 15;
    const int r0   = blockIdx.x * 128 + wave * 32;

    float4v acc[2][8];
    #pragma unroll
    for (int cg = 0; cg < 8; ++cg) {
        float bv = bias[cg * 16 + l16];
        float4v b4 = {bv, bv, bv, bv};
        acc[0][cg] = b4; acc[1][cg] = b4;
    }

    const short8* wp8 = (const short8*)Wp;

    #pragma unroll
    for (int kb = 0; kb < 8; ++kb) {
        const ushort_t* __restrict__ A = (kb < 4) ? A0 : A1;
        const int k0 = (kb & 3) * 32 + quad * 8;
        short8 a[2];
        #pragma unroll
        for (int rb = 0; rb < 2; ++rb) {
            int row = r0 + rb * 16 + l16;
            if (row >= N) row = N - 1;
            a[rb] = *(const short8*)&A[(size_t)row * D + k0];
        }
        #pragma unroll
        for (int cg = 0; cg < 8; ++cg) {
            short8 b = wp8[(kb * 8 + cg) * 64 + lane];
            acc[0][cg] = __builtin_amdgcn_mfma_f32_16x16x32_bf16(a[0], b, acc[0][cg], 0, 0, 0);
            acc[1][cg] = __builtin_amdgcn_mfma_f32_16x16x32_bf16(a[1], b, acc[1][cg], 0, 0, 0);
        }
    }

    #pragma unroll
    for (int rb = 0; rb < 2; ++rb) {
        int rowb = r0 + rb * 16 + quad * 4;
        #pragma unroll
        for (int cg = 0; cg < 8; ++cg) {
            int col = cg * 16 + l16;
            #pragma unroll
            for (int i = 0; i < 4; ++i) {
                int row = rowb + i;
                if (row < N) {
                    float v = acc[rb][cg][i];
                    Yf[(size_t)row * 256 + col] = v;
                    Ybf[(size_t)row * D + col] = f2bf(v);
                }
            }
        }
    }
}

// ---------------- K5/K7: gather-sum over CSR (bf16 msg), quad-split ---------
__global__ __launch_bounds__(256) void gather_bf(
    const ushort_t* __restrict__ msg,            // [N][128] bf16
    const int* __restrict__ offs, const int* __restrict__ bsrc,
    ushort_t* __restrict__ aggB,                 // bf16 out [N][128], or null
    float* __restrict__ aggF,                    // fp32 out (stride 256), or null
    int N)
{
    int node = (blockIdx.x * 256 + threadIdx.x) >> 6;
    int lane = threadIdx.x & 63;
    if (node >= N) return;
    const int quad = lane >> 4;
    const int c16  = lane & 15;
    int beg = offs[node], end = offs[node + 1];

    float ax[4] = {0.f, 0.f, 0.f, 0.f};
    float ay[4] = {0.f, 0.f, 0.f, 0.f};
    const uint4* mp = (const uint4*)msg;         // 16 uint4 per row

    for (int base = beg; base < end; base += 64) {
        int cnt = end - base; if (cnt > 64) cnt = 64;
        int sidx = bsrc[base + (lane < cnt ? lane : cnt - 1)];
        for (int j0 = 0; j0 < cnt; j0 += 16) {
            #pragma unroll
            for (int t = 0; t < 4; ++t) {
                int e  = j0 + t * 4 + quad;
                int ec = (e < cnt) ? e : cnt - 1;
                int s  = __shfl(sidx, ec, 64);
                uint4 u = mp[(size_t)s * 16 + c16];
                if (e < cnt) {
                    ax[0] += bflo(u.x); ay[0] += bfhi(u.x);
                    ax[1] += bflo(u.y); ay[1] += bfhi(u.y);
                    ax[2] += bflo(u.z); ay[2] += bfhi(u.z);
                    ax[3] += bflo(u.w); ay[3] += bfhi(u.w);
                }
            }
        }
    }

    #pragma unroll
    for (int k = 0; k < 4; ++k) {
        ax[k] += __shfl_xor(ax[k], 16, 64);
        ax[k] += __shfl_xor(ax[k], 32, 64);
        ay[k] += __shfl_xor(ay[k], 16, 64);
        ay[k] += __shfl_xor(ay[k], 32, 64);
    }

    if (quad == 0) {
        if (aggB) {
            uint4 o;
            o.x = (uint_t)f2bf(ax[0]) | ((uint_t)f2bf(ay[0]) << 16);
            o.y = (uint_t)f2bf(ax[1]) | ((uint_t)f2bf(ay[1]) << 16);
            o.z = (uint_t)f2bf(ax[2]) | ((uint_t)f2bf(ay[2]) << 16);
            o.w = (uint_t)f2bf(ax[3]) | ((uint_t)f2bf(ay[3]) << 16);
            ((uint4*)aggB)[(size_t)node * 16 + c16] = o;
        } else {
            float4 w0 = {ax[0], ay[0], ax[1], ay[1]};
            float4 w1 = {ax[2], ay[2], ax[3], ay[3]};
            float* p = &aggF[(size_t)node * 256 + c16 * 8];
            *(float4*)p = w0;
            *(float4*)(p + 4) = w1;
        }
    }
}

// ---------------------------------------------------------------------------
extern "C" void kernel_launch(void* const* d_in, const int* in_sizes, int n_in,
                              void* d_out, int out_size, void* d_ws, size_t ws_size,
                              hipStream_t stream) {
    const float* features = (const float*)d_in[0];
    const int*   src      = (const int*)d_in[1];
    const int*   dst      = (const int*)d_in[2];
    const float* W1       = (const float*)d_in[3];
    const float* b1       = (const float*)d_in[4];
    const float* W2       = (const float*)d_in[5];
    const float* b2       = (const float*)d_in[6];
    float* out = (float*)d_out;

    const int N = in_sizes[0] / D;   // 50000
    const int E = in_sizes[1];       // 800000
    const int NB = (N + 255) >> 8;   // 196 chunks of 256 nodes

    // ws carve-up (same footprint as prior rounds; tmp slot unused now)
    ushort_t* m1bf   = (ushort_t*)d_ws;                 // N*D
    ushort_t* agg1bf = m1bf + (size_t)N * D;            // N*D
    ushort_t* m2bf   = agg1bf + (size_t)N * D;          // N*D
    ushort_t* W1p    = m2bf + (size_t)N * D;            // 16384
    ushort_t* W2p    = W1p + 16384;                     // 32768
    int*  deg  = (int*)(W2p + 32768);                   // NB*256 (zero-padded)
    int*  cur  = deg + (size_t)NB * 256;                // NB*256
    int*  bb   = cur + (size_t)NB * 256;                // NB+1 (unused)
    int*  offs = bb + NB + 1;                           // N+1
    int2* tmp  = (int2*)(offs + N + 1);                 // E pairs (unused)
    int*  bsrc = (int*)(tmp + (size_t)E);               // E

    const int gemmBlocks = (N + 127) / 128;             // 391

    // K1: zero deg || weight pack
    zero_pack<<<NB + 24, 256, 0, stream>>>(W1, W2, W1p, W2p, deg, NB);
    // K2: in-degree histogram
    hist<<<256, 256, 0, stream>>>(dst, deg, E);
    // K3: scan -> offs + cur
    scanK<<<NB, 256, 0, stream>>>(deg, offs, cur, E, N, NB);
    // K4: edge scatter || layer-1 GEMM
    scatter_gemm1<<<SCB + gemmBlocks, 256, 0, stream>>>(
        src, dst, cur, bsrc, E, features, W1p, b1, m1bf, N);
    // K5: layer-1 gather -> agg1bf (bf16)
    gather_bf<<<(N * 64 + 255) / 256, 256, 0, stream>>>(m1bf, offs, bsrc,
                                                        agg1bf, nullptr, N);
    // K6: layer-2 GEMM -> out[:,128:] fp32 + m2bf
    gemm2_mfma<<<gemmBlocks, 256, 0, stream>>>(agg1bf, m1bf, W2p, b2,
                                               out + D, m2bf, N);
    // K7: layer-2 gather -> out[:, :128]
    gather_bf<<<(N * 64 + 255) / 256, 256, 0, stream>>>(m2bf, offs, bsrc,
                                                        nullptr, out, N);
}

// Round 6
// 205.451 us; speedup vs baseline: 1.4167x; 1.2363x over previous
//
#include <hip/hip_runtime.h>

// ---------------------------------------------------------------------------
// GNN 2-layer via bf16 MFMA + CSR gather (no global atomics).
// Round 6 = Round-2 structure (best measured, 208.5us) + 64-row GEMM tiles.
//  - R4/R5 atomic CSR build REVERTED: random 4B scattered stores cost 66MB
//    of write-allocate traffic (scatter_gemm1 = 51us). Counting sort wins.
//  - GEMMs re-tiled 128->64 rows/block (wave owns 16 rows, acc[8]):
//    391 -> 782 blocks = 3 blocks/CU, 2x waves for latency hiding.
// Launches:
//   K1: pack_w || binA
//   K2: binB (merged scans)
//   K3: binC || gemm1[0..gbA)
//   K4: binD || gemm1[gbA..)
//   K5: gather_bf (layer 1) -> agg1bf (bf16)
//   K6: gemm2_mfma -> out[:,128:] fp32 + m2bf
//   K7: gather_bf (layer 2) -> out[:, :128] fp32
// ws: m1bf | agg1bf | m2bf | W1p | W2p | mat | matc | bb | offs | tmp | bsrc
// ---------------------------------------------------------------------------

#define D 128
#define CBLK 256         // coarse-binning blocks (phases A and C)
#define DCAP 6144        // max edges per coarse bucket for LDS path

typedef __attribute__((ext_vector_type(8))) short short8;
typedef __attribute__((ext_vector_type(4))) float float4v;
typedef unsigned short ushort_t;
typedef unsigned int uint_t;

static __device__ __forceinline__ ushort_t f2bf(float f) {
    uint_t u = __builtin_bit_cast(uint_t, f);
    u += 0x7FFFu + ((u >> 16) & 1u);           // RNE
    return (ushort_t)(u >> 16);
}
static __device__ __forceinline__ float bfhi(uint_t u) {
    return __builtin_bit_cast(float, u & 0xFFFF0000u);
}
static __device__ __forceinline__ float bflo(uint_t u) {
    return __builtin_bit_cast(float, u << 16);
}

// ---------------- shared gemm1 body: 64-row tile, wave = 16 rows ------------
static __device__ __forceinline__ void gemm1_body(
    const float* __restrict__ X, const ushort_t* __restrict__ Wp,
    const float* __restrict__ bias, ushort_t* __restrict__ Ybf,
    int N, int gb)
{
    const int wave = threadIdx.x >> 6;
    const int lane = threadIdx.x & 63;
    const int quad = lane >> 4;
    const int l16  = lane & 15;
    const int r0   = gb * 64 + wave * 16;

    float4v acc[8];
    #pragma unroll
    for (int cg = 0; cg < 8; ++cg) {
        float bv = bias[cg * 16 + l16];
        float4v b4 = {bv, bv, bv, bv};
        acc[cg] = b4;
    }

    const short8* wp8 = (const short8*)Wp;

    #pragma unroll
    for (int kb = 0; kb < 4; ++kb) {
        const int k0 = kb * 32 + quad * 8;
        int row = r0 + l16;
        if (row >= N) row = N - 1;
        const float* p = &X[(size_t)row * D + k0];
        float4 x0 = *(const float4*)p;
        float4 x1 = *(const float4*)(p + 4);
        short8 a;
        a[0] = (short)f2bf(x0.x); a[1] = (short)f2bf(x0.y);
        a[2] = (short)f2bf(x0.z); a[3] = (short)f2bf(x0.w);
        a[4] = (short)f2bf(x1.x); a[5] = (short)f2bf(x1.y);
        a[6] = (short)f2bf(x1.z); a[7] = (short)f2bf(x1.w);
        #pragma unroll
        for (int cg = 0; cg < 8; ++cg) {
            short8 b = wp8[(kb * 8 + cg) * 64 + lane];
            acc[cg] = __builtin_amdgcn_mfma_f32_16x16x32_bf16(a, b, acc[cg], 0, 0, 0);
        }
    }

    const int rowb = r0 + quad * 4;
    #pragma unroll
    for (int cg = 0; cg < 8; ++cg) {
        int col = cg * 16 + l16;
        #pragma unroll
        for (int i = 0; i < 4; ++i) {
            int row = rowb + i;
            if (row < N) Ybf[(size_t)row * D + col] = f2bf(acc[cg][i]);
        }
    }
}

// ---------------- K1: pack both W (B-frag layout)  ||  binA -----------------
__global__ __launch_bounds__(256) void packw_binA(
    const float* __restrict__ W1, const float* __restrict__ W2,
    ushort_t* __restrict__ W1p, ushort_t* __restrict__ W2p,
    const int* __restrict__ dst, int* __restrict__ mat, int E, int NB)
{
    __shared__ int h[256];
    if (blockIdx.x < CBLK) {
        const int c = blockIdx.x;
        for (int i = threadIdx.x; i < NB; i += 256) h[i] = 0;
        __syncthreads();
        const int chunk = (E + CBLK - 1) / CBLK;
        int e0 = c * chunk, e1 = e0 + chunk; if (e1 > E) e1 = E;
        for (int e = e0 + threadIdx.x; e < e1; e += 256)
            atomicAdd(&h[dst[e] >> 8], 1);
        __syncthreads();
        for (int i = threadIdx.x; i < NB; i += 256)
            mat[i * CBLK + c] = h[i];
        return;
    }
    const int n1 = 4 * 8 * 64;
    const int n2 = 8 * 8 * 64;
    int t = (blockIdx.x - CBLK) * 256 + threadIdx.x;
    if (t >= n1 + n2) return;
    const float* W; ushort_t* Wp; int tt;
    if (t < n1) { W = W1; Wp = W1p; tt = t; }
    else        { W = W2; Wp = W2p; tt = t - n1; }
    int lane = tt & 63, cg = (tt >> 6) & 7, kb = tt >> 9;
    int krow = kb * 32 + (lane >> 4) * 8;
    int col  = cg * 16 + (lane & 15);
    #pragma unroll
    for (int j = 0; j < 8; ++j)
        Wp[(size_t)tt * 8 + j] = f2bf(W[(size_t)(krow + j) * D + col]);
}

// ---------------- K2: binB (merged B1+B2) -----------------------------------
__global__ __launch_bounds__(256) void binB(
    const int* __restrict__ mat, int* __restrict__ matc,
    int* __restrict__ bb, int* __restrict__ offs, int E, int N, int NB)
{
    __shared__ int s[256];
    __shared__ int ex[256];
    const int b = blockIdx.x;
    const int tid = threadIdx.x;

    int v = 0;
    if (tid < NB) {
        const int* row = &mat[tid * CBLK];
        for (int c = 0; c < CBLK; ++c) v += row[c];
    }
    s[tid] = v; __syncthreads();
    for (int o = 1; o < 256; o <<= 1) {
        int t = (tid >= o) ? s[tid - o] : 0;
        __syncthreads();
        s[tid] += t;
        __syncthreads();
    }
    ex[tid] = s[tid] - v;
    __syncthreads();
    if (b == 0) {
        if (tid < NB) bb[tid] = ex[tid];
        if (tid == 0) { bb[NB] = E; offs[N] = E; }
    }
    const int bbb = ex[b];

    int v2 = mat[b * CBLK + tid];
    __syncthreads();
    s[tid] = v2; __syncthreads();
    for (int o = 1; o < 256; o <<= 1) {
        int t = (tid >= o) ? s[tid - o] : 0;
        __syncthreads();
        s[tid] += t;
        __syncthreads();
    }
    matc[b * CBLK + tid] = bbb + s[tid] - v2;
}

// ---------------- K3: binC  ||  gemm1 part A --------------------------------
__global__ __launch_bounds__(256) void binC_gemm1(
    const int* __restrict__ src, const int* __restrict__ dst,
    const int* __restrict__ matc, int2* __restrict__ tmp, int E, int NB,
    const float* __restrict__ X, const ushort_t* __restrict__ Wp,
    const float* __restrict__ bias, ushort_t* __restrict__ Ybf, int N)
{
    __shared__ int base[256];
    __shared__ int lcnt[256];
    if (blockIdx.x < CBLK) {
        const int c = blockIdx.x;
        for (int i = threadIdx.x; i < NB; i += 256) {
            base[i] = matc[i * CBLK + c];
            lcnt[i] = 0;
        }
        __syncthreads();
        const int chunk = (E + CBLK - 1) / CBLK;
        int e0 = c * chunk, e1 = e0 + chunk; if (e1 > E) e1 = E;
        for (int e = e0 + threadIdx.x; e < e1; e += 256) {
            int d = dst[e];
            int b = d >> 8;
            int p = base[b] + atomicAdd(&lcnt[b], 1);
            int2 pr; pr.x = d; pr.y = src[e];
            tmp[p] = pr;
        }
        return;
    }
    gemm1_body(X, Wp, bias, Ybf, N, blockIdx.x - CBLK);
}

// ---------------- K4: binD (fine sort) || gemm1 part B ----------------------
__global__ __launch_bounds__(256) void binD_gemm1(
    const int2* __restrict__ tmp, const int* __restrict__ bb,
    int* __restrict__ offs, int* __restrict__ bsrc, int N, int NB,
    const float* __restrict__ X, const ushort_t* __restrict__ Wp,
    const float* __restrict__ bias, ushort_t* __restrict__ Ybf, int gb0)
{
    __shared__ int hist[256];
    __shared__ int foff[256];
    __shared__ int cntf[256];
    __shared__ int outS[DCAP];
    if (blockIdx.x >= (uint_t)NB) {
        gemm1_body(X, Wp, bias, Ybf, N, blockIdx.x - NB + gb0);
        return;
    }
    const int b = blockIdx.x;
    const int tid = threadIdx.x;
    const int beg = bb[b], end = bb[b + 1];
    const int cnt = end - beg;
    const int n0 = b << 8;

    hist[tid] = 0;
    __syncthreads();
    for (int i = tid; i < cnt; i += 256)
        atomicAdd(&hist[tmp[beg + i].x & 255], 1);
    __syncthreads();
    int v = hist[tid];
    __syncthreads();
    hist[tid] = v; __syncthreads();
    for (int o = 1; o < 256; o <<= 1) {
        int t = (tid >= o) ? hist[tid - o] : 0;
        __syncthreads();
        hist[tid] += t;
        __syncthreads();
    }
    foff[tid] = hist[tid] - v;
    cntf[tid] = 0;
    __syncthreads();

    int node = n0 + tid;
    if (node < N) offs[node] = beg + foff[tid];

    if (cnt <= DCAP) {
        for (int i = tid; i < cnt; i += 256) {
            int2 p = tmp[beg + i];
            int f = p.x & 255;
            int pos = foff[f] + atomicAdd(&cntf[f], 1);
            outS[pos] = p.y;
        }
        __syncthreads();
        for (int i = tid; i < cnt; i += 256)
            bsrc[beg + i] = outS[i];
    } else {
        for (int i = tid; i < cnt; i += 256) {
            int2 p = tmp[beg + i];
            int f = p.x & 255;
            int pos = foff[f] + atomicAdd(&cntf[f], 1);
            bsrc[beg + pos] = p.y;
        }
    }
}

// ---------------- K6: MFMA GEMM 2 (64-row tile): bf16 A0/A1 -> fp32 + bf16 --
__global__ __launch_bounds__(256) void gemm2_mfma(
    const ushort_t* __restrict__ A0, const ushort_t* __restrict__ A1,
    const ushort_t* __restrict__ Wp, const float* __restrict__ bias,
    float* __restrict__ Yf, ushort_t* __restrict__ Ybf, int N)
{
    const int wave = threadIdx.x >> 6;
    const int lane = threadIdx.x & 63;
    const int quad = lane >> 4;
    const int l16  = lane & 15;
    const int r0   = blockIdx.x * 64 + wave * 16;

    float4v acc[8];
    #pragma unroll
    for (int cg = 0; cg < 8; ++cg) {
        float bv = bias[cg * 16 + l16];
        float4v b4 = {bv, bv, bv, bv};
        acc[cg] = b4;
    }

    const short8* wp8 = (const short8*)Wp;

    #pragma unroll
    for (int kb = 0; kb < 8; ++kb) {
        const ushort_t* __restrict__ A = (kb < 4) ? A0 : A1;
        const int k0 = (kb & 3) * 32 + quad * 8;
        int row = r0 + l16;
        if (row >= N) row = N - 1;
        short8 a = *(const short8*)&A[(size_t)row * D + k0];
        #pragma unroll
        for (int cg = 0; cg < 8; ++cg) {
            short8 b = wp8[(kb * 8 + cg) * 64 + lane];
            acc[cg] = __builtin_amdgcn_mfma_f32_16x16x32_bf16(a, b, acc[cg], 0, 0, 0);
        }
    }

    const int rowb = r0 + quad * 4;
    #pragma unroll
    for (int cg = 0; cg < 8; ++cg) {
        int col = cg * 16 + l16;
        #pragma unroll
        for (int i = 0; i < 4; ++i) {
            int row = rowb + i;
            if (row < N) {
                float v = acc[cg][i];
                Yf[(size_t)row * 256 + col] = v;
                Ybf[(size_t)row * D + col] = f2bf(v);
            }
        }
    }
}

// ---------------- K5/K7: gather-sum over CSR (bf16 msg), quad-split ---------
__global__ __launch_bounds__(256) void gather_bf(
    const ushort_t* __restrict__ msg,            // [N][128] bf16
    const int* __restrict__ offs, const int* __restrict__ bsrc,
    ushort_t* __restrict__ aggB,                 // bf16 out [N][128], or null
    float* __restrict__ aggF,                    // fp32 out (stride 256), or null
    int N)
{
    int node = (blockIdx.x * 256 + threadIdx.x) >> 6;
    int lane = threadIdx.x & 63;
    if (node >= N) return;
    const int quad = lane >> 4;
    const int c16  = lane & 15;
    int beg = offs[node], end = offs[node + 1];

    float ax[4] = {0.f, 0.f, 0.f, 0.f};
    float ay[4] = {0.f, 0.f, 0.f, 0.f};
    const uint4* mp = (const uint4*)msg;         // 16 uint4 per row

    for (int base = beg; base < end; base += 64) {
        int cnt = end - base; if (cnt > 64) cnt = 64;
        int sidx = bsrc[base + (lane < cnt ? lane : cnt - 1)];
        for (int j0 = 0; j0 < cnt; j0 += 16) {
            #pragma unroll
            for (int t = 0; t < 4; ++t) {
                int e  = j0 + t * 4 + quad;
                int ec = (e < cnt) ? e : cnt - 1;
                int s  = __shfl(sidx, ec, 64);
                uint4 u = mp[(size_t)s * 16 + c16];
                if (e < cnt) {
                    ax[0] += bflo(u.x); ay[0] += bfhi(u.x);
                    ax[1] += bflo(u.y); ay[1] += bfhi(u.y);
                    ax[2] += bflo(u.z); ay[2] += bfhi(u.z);
                    ax[3] += bflo(u.w); ay[3] += bfhi(u.w);
                }
            }
        }
    }

    #pragma unroll
    for (int k = 0; k < 4; ++k) {
        ax[k] += __shfl_xor(ax[k], 16, 64);
        ax[k] += __shfl_xor(ax[k], 32, 64);
        ay[k] += __shfl_xor(ay[k], 16, 64);
        ay[k] += __shfl_xor(ay[k], 32, 64);
    }

    if (quad == 0) {
        if (aggB) {
            uint4 o;
            o.x = (uint_t)f2bf(ax[0]) | ((uint_t)f2bf(ay[0]) << 16);
            o.y = (uint_t)f2bf(ax[1]) | ((uint_t)f2bf(ay[1]) << 16);
            o.z = (uint_t)f2bf(ax[2]) | ((uint_t)f2bf(ay[2]) << 16);
            o.w = (uint_t)f2bf(ax[3]) | ((uint_t)f2bf(ay[3]) << 16);
            ((uint4*)aggB)[(size_t)node * 16 + c16] = o;
        } else {
            float4 w0 = {ax[0], ay[0], ax[1], ay[1]};
            float4 w1 = {ax[2], ay[2], ax[3], ay[3]};
            float* p = &aggF[(size_t)node * 256 + c16 * 8];
            *(float4*)p = w0;
            *(float4*)(p + 4) = w1;
        }
    }
}

// ---------------------------------------------------------------------------
extern "C" void kernel_launch(void* const* d_in, const int* in_sizes, int n_in,
                              void* d_out, int out_size, void* d_ws, size_t ws_size,
                              hipStream_t stream) {
    const float* features = (const float*)d_in[0];
    const int*   src      = (const int*)d_in[1];
    const int*   dst      = (const int*)d_in[2];
    const float* W1       = (const float*)d_in[3];
    const float* b1       = (const float*)d_in[4];
    const float* W2       = (const float*)d_in[5];
    const float* b2       = (const float*)d_in[6];
    float* out = (float*)d_out;

    const int N = in_sizes[0] / D;   // 50000
    const int E = in_sizes[1];       // 800000
    const int NB = (N + 255) >> 8;   // 196 coarse buckets (<=256 required)

    // ws carve-up
    ushort_t* m1bf   = (ushort_t*)d_ws;                 // N*D
    ushort_t* agg1bf = m1bf + (size_t)N * D;            // N*D
    ushort_t* m2bf   = agg1bf + (size_t)N * D;          // N*D
    ushort_t* W1p    = m2bf + (size_t)N * D;            // 16384
    ushort_t* W2p    = W1p + 16384;                     // 32768
    int*  mat  = (int*)(W2p + 32768);                   // NB*CBLK (histograms)
    int*  matc = mat + (size_t)NB * CBLK;               // NB*CBLK (cursors)
    int*  bb   = matc + (size_t)NB * CBLK;              // NB+1
    int*  offs = bb + NB + 1;                           // N+1
    int2* tmp  = (int2*)(offs + N + 1);                 // E pairs
    int*  bsrc = (int*)(tmp + (size_t)E);               // E

    const int gemmBlocks = (N + 63) / 64;               // 782 (64-row tiles)
    const int gbA = (gemmBlocks * 3) / 5;               // gemm1 share in K3

    // K1: weight pack || coarse histogram
    packw_binA<<<CBLK + 24, 256, 0, stream>>>(W1, W2, W1p, W2p, dst, mat, E, NB);
    // K2: merged scans -> bucket bases (bb) + per-block cursors (matc)
    binB<<<NB, 256, 0, stream>>>(mat, matc, bb, offs, E, N, NB);
    // K3: coarse binning || gemm1 tiles [0, gbA)
    binC_gemm1<<<CBLK + gbA, 256, 0, stream>>>(src, dst, matc, tmp, E, NB,
                                               features, W1p, b1, m1bf, N);
    // K4: fine sort || gemm1 tiles [gbA, gemmBlocks)
    binD_gemm1<<<NB + (gemmBlocks - gbA), 256, 0, stream>>>(
        tmp, bb, offs, bsrc, N, NB, features, W1p, b1, m1bf, gbA);
    // K5: layer-1 gather -> agg1bf (bf16)
    gather_bf<<<(N * 64 + 255) / 256, 256, 0, stream>>>(m1bf, offs, bsrc,
                                                        agg1bf, nullptr, N);
    // K6: layer-2 GEMM -> out[:,128:] fp32 + m2bf
    gemm2_mfma<<<gemmBlocks, 256, 0, stream>>>(agg1bf, m1bf, W2p, b2,
                                               out + D, m2bf, N);
    // K7: layer-2 gather -> out[:, :128]
    gather_bf<<<(N * 64 + 255) / 256, 256, 0, stream>>>(m2bf, offs, bsrc,
                                                        nullptr, out, N);
}